// Round 1
// baseline (99.935 us; speedup 1.0000x reference)
//
#include <hip/hip_runtime.h>
#include <hip/hip_bf16.h>
#include <cstdint>
#include <cstddef>

#define B_ 64
#define T_ 256
#define C_ 384
#define H_ 6
#define HD_ 64

using u16 = unsigned short;
typedef __attribute__((ext_vector_type(8))) short short8;   // 8 bf16 (4 VGPR)
typedef __attribute__((ext_vector_type(4))) short short4_;  // 4 bf16 (8 B)
typedef __attribute__((ext_vector_type(4))) float f32x4;

__device__ __forceinline__ u16 f2bf(float f) {
    union { float f; uint32_t u; } x{f};
    uint32_t r = x.u + 0x7fffu + ((x.u >> 16) & 1u);
    return (u16)(r >> 16);
}

// ---------------- converts / packs ----------------

__global__ void k_cvt(const float* __restrict__ in, u16* __restrict__ out, int n) {
    int i = (blockIdx.x * blockDim.x + threadIdx.x) * 8;
    if (i >= n) return;
    const f32x4* p = (const f32x4*)(in + i);
    f32x4 a = p[0], b = p[1];
    short8 s;
    s[0] = (short)f2bf(a[0]); s[1] = (short)f2bf(a[1]);
    s[2] = (short)f2bf(a[2]); s[3] = (short)f2bf(a[3]);
    s[4] = (short)f2bf(b[0]); s[5] = (short)f2bf(b[1]);
    s[6] = (short)f2bf(b[2]); s[7] = (short)f2bf(b[3]);
    *(short8*)(out + i) = s;
}

// Build packed n-major weight matrix [N=1152][K=384]:
// n = which*384 + h*64 + d ; element = W_which[h][c][d]
__global__ void k_pack_qkv(const float* __restrict__ Wq, const float* __restrict__ Wk,
                           const float* __restrict__ Wv, u16* __restrict__ out) {
    int i = blockIdx.x * 256 + threadIdx.x;  // 0 .. 1152*384-1
    int n = i / 384, cc = i % 384;
    int which = n / 384, rem = n % 384;
    int h = rem / 64, d = rem % 64;
    const float* W = (which == 0) ? Wq : ((which == 1) ? Wk : Wv);
    out[i] = f2bf(W[(h * 384 + cc) * 64 + d]);
}

// ---------------- QKV GEMM: M=16384, N=1152, K=384 ----------------
// A = x_bf16 [M][384] row-major ; B = wqkv [N][384] n-major
// out: q/k/v bf16 each [B,H,T,HD]
__global__ __launch_bounds__(256) void k_gemm_qkv(const u16* __restrict__ xb, const u16* __restrict__ wb,
                                                  u16* __restrict__ q, u16* __restrict__ k,
                                                  u16* __restrict__ v) {
    __shared__ u16 As[128 * 40];
    __shared__ u16 Bs[64 * 40];
    const int tid = threadIdx.x;
    const int n0 = blockIdx.x * 64;   // 0..1088
    const int m0 = blockIdx.y * 128;
    const int lane = tid & 63, wid = tid >> 6;
    const int wm = wid >> 1, wn = wid & 1;
    const int g = lane >> 4, c = lane & 15;
    f32x4 acc[4][2] = {};
    for (int kt = 0; kt < 12; ++kt) {
        const int k0 = kt * 32;
#pragma unroll
        for (int i = 0; i < 2; ++i) {
            int idx = tid + i * 256;
            int row = idx >> 2, c8 = (idx & 3) * 8;
            *(short8*)&As[row * 40 + c8] = *(const short8*)&xb[(m0 + row) * 384 + k0 + c8];
        }
        {
            int row = tid >> 2, c8 = (tid & 3) * 8;
            *(short8*)&Bs[row * 40 + c8] = *(const short8*)&wb[(n0 + row) * 384 + k0 + c8];
        }
        __syncthreads();
        short8 af[4];
#pragma unroll
        for (int mf = 0; mf < 4; ++mf)
            af[mf] = *(short8*)&As[(wm * 64 + mf * 16 + c) * 40 + g * 8];
#pragma unroll
        for (int nf = 0; nf < 2; ++nf) {
            short8 bfr = *(short8*)&Bs[(wn * 32 + nf * 16 + c) * 40 + g * 8];
#pragma unroll
            for (int mf = 0; mf < 4; ++mf)
                acc[mf][nf] = __builtin_amdgcn_mfma_f32_16x16x32_bf16(af[mf], bfr, acc[mf][nf], 0, 0, 0);
        }
        __syncthreads();
    }
    const int which = n0 / 384;
    const int h = (n0 % 384) / 64;
    u16* dst = (which == 0) ? q : ((which == 1) ? k : v);
#pragma unroll
    for (int mf = 0; mf < 4; ++mf)
#pragma unroll
        for (int nf = 0; nf < 2; ++nf)
#pragma unroll
            for (int r = 0; r < 4; ++r) {
                int m = m0 + wm * 64 + mf * 16 + g * 4 + r;
                int d = wn * 32 + nf * 16 + c;          // 0..63
                int b = m >> 8, t = m & 255;
                dst[((b * H_ + h) * T_ + t) * HD_ + d] = f2bf(acc[mf][nf][r]);
            }
}

// ---------------- fused causal attention, one block per (b,h) ----------------
// 4 waves; wave w owns q rows [64w,64w+64). Flash over 4 KV tiles of 64.
// S^T = K * Q^T so softmax rows are lane-local-ish; P^T packs to b64 LDS writes.
__global__ __launch_bounds__(256, 1) void k_attn(const u16* __restrict__ q, const u16* __restrict__ k,
                                                 const u16* __restrict__ v, u16* __restrict__ ao) {
    __shared__ u16 Kt[64 * 72];        // [s][c] stride 72
    __shared__ u16 Vt[64 * 72];        // transposed: [d][s] stride 72
    __shared__ u16 Ps[4][64 * 72];     // per wave: [q][s] stride 72
    const int tid = threadIdx.x, bh = blockIdx.x;
    const int lane = tid & 63, wid = tid >> 6;
    const int g = lane >> 4, c = lane & 15;
    const int bq = bh * 256;

    short8 qB[4][2];
#pragma unroll
    for (int qf = 0; qf < 4; ++qf)
#pragma unroll
        for (int ks = 0; ks < 2; ++ks) {
            int t = wid * 64 + qf * 16 + c;
            qB[qf][ks] = *(const short8*)&q[(bq + t) * 64 + ks * 32 + g * 8];
        }
    float mrun[4], lrun[4];
#pragma unroll
    for (int i = 0; i < 4; ++i) { mrun[i] = -1e30f; lrun[i] = 0.f; }
    f32x4 o[4][4] = {};

    for (int kt = 0; kt < 4; ++kt) {
        // stage K normal (coalesced), V transposed (conflict-free via row-major lanes)
#pragma unroll
        for (int i = 0; i < 2; ++i) {
            int idx = tid + i * 256;
            int row = idx >> 3, c8 = (idx & 7) * 8;
            *(short8*)&Kt[row * 72 + c8] = *(const short8*)&k[(bq + kt * 64 + row) * 64 + c8];
            int vrow = idx & 63, vc8 = (idx >> 6) * 8;
            short8 vv = *(const short8*)&v[(bq + kt * 64 + vrow) * 64 + vc8];
#pragma unroll
            for (int j = 0; j < 8; ++j)
                Vt[(vc8 + j) * 72 + vrow] = (u16)vv[j];
        }
        __syncthreads();
        if (kt <= wid) {
            f32x4 st[4][4] = {};
#pragma unroll
            for (int ks = 0; ks < 2; ++ks) {
                short8 kA[4];
#pragma unroll
                for (int sf = 0; sf < 4; ++sf)
                    kA[sf] = *(short8*)&Kt[(sf * 16 + c) * 72 + ks * 32 + g * 8];
#pragma unroll
                for (int sf = 0; sf < 4; ++sf)
#pragma unroll
                    for (int qf = 0; qf < 4; ++qf)
                        st[sf][qf] = __builtin_amdgcn_mfma_f32_16x16x32_bf16(kA[sf], qB[qf][ks], st[sf][qf], 0, 0, 0);
            }
            float pm[4] = {-1e30f, -1e30f, -1e30f, -1e30f};
#pragma unroll
            for (int sf = 0; sf < 4; ++sf)
#pragma unroll
                for (int qf = 0; qf < 4; ++qf)
#pragma unroll
                    for (int r = 0; r < 4; ++r) {
                        float val = st[sf][qf][r] * 0.125f;
                        if (kt == wid) {
                            int s_loc = sf * 16 + g * 4 + r, q_loc = qf * 16 + c;
                            if (s_loc > q_loc) val = -1e30f;
                        }
                        st[sf][qf][r] = val;
                        pm[qf] = fmaxf(pm[qf], val);
                    }
            float alpha[4], lsum[4];
#pragma unroll
            for (int qf = 0; qf < 4; ++qf) {
                pm[qf] = fmaxf(pm[qf], __shfl_xor(pm[qf], 16));
                pm[qf] = fmaxf(pm[qf], __shfl_xor(pm[qf], 32));
                float mnew = fmaxf(mrun[qf], pm[qf]);
                alpha[qf] = __expf(mrun[qf] - mnew);
                mrun[qf] = mnew;
                lsum[qf] = 0.f;
            }
            u16* myPs = Ps[wid];
#pragma unroll
            for (int sf = 0; sf < 4; ++sf)
#pragma unroll
                for (int qf = 0; qf < 4; ++qf) {
                    short4_ pb;
                    float s4 = 0.f;
#pragma unroll
                    for (int r = 0; r < 4; ++r) {
                        float p = __expf(st[sf][qf][r] - mrun[qf]);
                        s4 += p;
                        pb[r] = (short)f2bf(p);
                    }
                    lsum[qf] += s4;
                    *(short4_*)&myPs[(qf * 16 + c) * 72 + sf * 16 + g * 4] = pb;
                }
#pragma unroll
            for (int qf = 0; qf < 4; ++qf) {
                lsum[qf] += __shfl_xor(lsum[qf], 16);
                lsum[qf] += __shfl_xor(lsum[qf], 32);
                lrun[qf] = lrun[qf] * alpha[qf] + lsum[qf];
            }
            // rescale O (row q = mf*16 + g*4 + r -> stats live at lane g*4+r, reg mf)
#pragma unroll
            for (int mf = 0; mf < 4; ++mf)
#pragma unroll
                for (int r = 0; r < 4; ++r) {
                    float aof = __shfl(alpha[mf], g * 4 + r);
#pragma unroll
                    for (int df = 0; df < 4; ++df)
                        o[mf][df][r] *= aof;
                }
            // PV
#pragma unroll
            for (int ks = 0; ks < 2; ++ks) {
                short8 vB[4], pA[4];
#pragma unroll
                for (int df = 0; df < 4; ++df)
                    vB[df] = *(short8*)&Vt[(df * 16 + c) * 72 + ks * 32 + g * 8];
#pragma unroll
                for (int mf = 0; mf < 4; ++mf)
                    pA[mf] = *(short8*)&myPs[(mf * 16 + c) * 72 + ks * 32 + g * 8];
#pragma unroll
                for (int mf = 0; mf < 4; ++mf)
#pragma unroll
                    for (int df = 0; df < 4; ++df)
                        o[mf][df] = __builtin_amdgcn_mfma_f32_16x16x32_bf16(pA[mf], vB[df], o[mf][df], 0, 0, 0);
            }
        }
        __syncthreads();
    }
    const int bb = bh / H_, hh = bh % H_;
#pragma unroll
    for (int mf = 0; mf < 4; ++mf)
#pragma unroll
        for (int r = 0; r < 4; ++r) {
            float inv = 1.0f / __shfl(lrun[mf], g * 4 + r);
            int t = wid * 64 + mf * 16 + g * 4 + r;
#pragma unroll
            for (int df = 0; df < 4; ++df) {
                int d = df * 16 + c;
                ao[((size_t)(bb * T_ + t)) * C_ + hh * 64 + d] = f2bf(o[mf][df][r] * inv);
            }
        }
}

// ---------------- output projection: M=16384, N=384, K=384, + bias, fp32 out ----------------
__global__ __launch_bounds__(256) void k_gemm_proj(const u16* __restrict__ ab, const u16* __restrict__ wp,
                                                   const float* __restrict__ bp, float* __restrict__ out) {
    __shared__ u16 As[128 * 40];
    __shared__ u16 Bs[64 * 40];
    const int tid = threadIdx.x;
    const int n0 = blockIdx.x * 64;   // 0..320
    const int m0 = blockIdx.y * 128;
    const int lane = tid & 63, wid = tid >> 6;
    const int wm = wid >> 1, wn = wid & 1;
    const int g = lane >> 4, c = lane & 15;
    f32x4 acc[4][2] = {};
    for (int kt = 0; kt < 12; ++kt) {
        const int k0 = kt * 32;
#pragma unroll
        for (int i = 0; i < 2; ++i) {
            int idx = tid + i * 256;
            int row = idx >> 2, c8 = (idx & 3) * 8;
            *(short8*)&As[row * 40 + c8] = *(const short8*)&ab[(m0 + row) * 384 + k0 + c8];
        }
        {
            int row = tid >> 2, c8 = (tid & 3) * 8;
            *(short8*)&Bs[row * 40 + c8] = *(const short8*)&wp[(n0 + row) * 384 + k0 + c8];
        }
        __syncthreads();
        short8 af[4];
#pragma unroll
        for (int mf = 0; mf < 4; ++mf)
            af[mf] = *(short8*)&As[(wm * 64 + mf * 16 + c) * 40 + g * 8];
#pragma unroll
        for (int nf = 0; nf < 2; ++nf) {
            short8 bfr = *(short8*)&Bs[(wn * 32 + nf * 16 + c) * 40 + g * 8];
#pragma unroll
            for (int mf = 0; mf < 4; ++mf)
                acc[mf][nf] = __builtin_amdgcn_mfma_f32_16x16x32_bf16(af[mf], bfr, acc[mf][nf], 0, 0, 0);
        }
        __syncthreads();
    }
#pragma unroll
    for (int mf = 0; mf < 4; ++mf)
#pragma unroll
        for (int nf = 0; nf < 2; ++nf)
#pragma unroll
            for (int r = 0; r < 4; ++r) {
                int m = m0 + wm * 64 + mf * 16 + g * 4 + r;
                int n = n0 + wn * 32 + nf * 16 + c;
                out[(size_t)m * C_ + n] = acc[mf][nf][r] + bp[n];
            }
}

// ---------------- host ----------------

extern "C" void kernel_launch(void* const* d_in, const int* in_sizes, int n_in,
                              void* d_out, int out_size, void* d_ws, size_t ws_size,
                              hipStream_t stream) {
    const float* x  = (const float*)d_in[0];
    const float* Wq = (const float*)d_in[1];
    const float* Wk = (const float*)d_in[2];
    const float* Wv = (const float*)d_in[3];
    const float* Wp = (const float*)d_in[4];
    const float* bp = (const float*)d_in[5];
    float* out = (float*)d_out;

    char* ws = (char*)d_ws;
    u16* xb   = (u16*)(ws);                    // 16384*384       = 6291456  (12.6 MB)
    u16* wqkv = (u16*)(ws + 12582912);         // 1152*384        = 442368
    u16* wpb  = (u16*)(ws + 13467648);         // 384*384         = 147456
    u16* qb   = (u16*)(ws + 13762560);         // 64*6*256*64
    u16* kb   = (u16*)(ws + 26345472);
    u16* vb   = (u16*)(ws + 38928384);
    u16* ab   = (u16*)(ws + 51511296);         // 16384*384 bf16
    // total 64,094,208 bytes

    k_cvt<<<3072, 256, 0, stream>>>(x, xb, 16384 * 384);
    k_pack_qkv<<<1728, 256, 0, stream>>>(Wq, Wk, Wv, wqkv);
    k_cvt<<<72, 256, 0, stream>>>(Wp, wpb, 384 * 384);
    k_gemm_qkv<<<dim3(18, 128), 256, 0, stream>>>(xb, wqkv, qb, kb, vb);
    k_attn<<<384, 256, 0, stream>>>(qb, kb, vb, ab);
    k_gemm_proj<<<dim3(6, 128), 256, 0, stream>>>(ab, wpb, bp, out);
}

// Round 2
// 85.676 us; speedup vs baseline: 1.1664x; 1.1664x over previous
//
#include <hip/hip_runtime.h>
#include <hip/hip_bf16.h>
#include <cstdint>
#include <cstddef>

#define B_ 64
#define T_ 256
#define C_ 384
#define H_ 6
#define HD_ 64

using u16 = unsigned short;
typedef __attribute__((ext_vector_type(8))) short short8;   // 8 bf16 (4 VGPR)
typedef __attribute__((ext_vector_type(4))) short short4_;  // 4 bf16 (8 B)
typedef __attribute__((ext_vector_type(4))) float f32x4;

__device__ __forceinline__ u16 f2bf(float f) {
    union { float f; uint32_t u; } x{f};
    uint32_t r = x.u + 0x7fffu + ((x.u >> 16) & 1u);
    return (u16)(r >> 16);
}

// ---------------- fused prep: cvt x, pack Wqkv, cvt Wp ----------------
// blocks [0,3072): x -> xb (8 elems/thread)
// blocks [3072,4800): pack Wq/Wk/Wv -> wqkv [1152][384] n-major
// blocks [4800,4872): Wp -> wpb
__global__ void k_prep(const float* __restrict__ x, const float* __restrict__ Wq,
                       const float* __restrict__ Wk, const float* __restrict__ Wv,
                       const float* __restrict__ Wp, u16* __restrict__ xb,
                       u16* __restrict__ wqkv, u16* __restrict__ wpb) {
    int bid = blockIdx.x;
    if (bid < 3072) {
        int i = (bid * 256 + threadIdx.x) * 8;
        const f32x4* p = (const f32x4*)(x + i);
        f32x4 a = p[0], b = p[1];
        short8 s;
        s[0] = (short)f2bf(a[0]); s[1] = (short)f2bf(a[1]);
        s[2] = (short)f2bf(a[2]); s[3] = (short)f2bf(a[3]);
        s[4] = (short)f2bf(b[0]); s[5] = (short)f2bf(b[1]);
        s[6] = (short)f2bf(b[2]); s[7] = (short)f2bf(b[3]);
        *(short8*)(xb + i) = s;
    } else if (bid < 4800) {
        int i = (bid - 3072) * 256 + threadIdx.x;  // 0 .. 1152*384-1
        int n = i / 384, cc = i % 384;
        int which = n / 384, rem = n % 384;
        int h = rem / 64, d = rem % 64;
        const float* W = (which == 0) ? Wq : ((which == 1) ? Wk : Wv);
        wqkv[i] = f2bf(W[(h * 384 + cc) * 64 + d]);
    } else {
        int i = ((bid - 4800) * 256 + threadIdx.x) * 8;
        const f32x4* p = (const f32x4*)(Wp + i);
        f32x4 a = p[0], b = p[1];
        short8 s;
        s[0] = (short)f2bf(a[0]); s[1] = (short)f2bf(a[1]);
        s[2] = (short)f2bf(a[2]); s[3] = (short)f2bf(a[3]);
        s[4] = (short)f2bf(b[0]); s[5] = (short)f2bf(b[1]);
        s[6] = (short)f2bf(b[2]); s[7] = (short)f2bf(b[3]);
        *(short8*)(wpb + i) = s;
    }
}

// ---------------- GEMM core: 128x128 tile, BK=64, global_load_lds + swizzle ----------------
// LDS tile layout: [128 rows][8 slots of 16B]; logical (row,slot) stored at
// physical pslot = slot ^ (row&7). global_load_lds writes linearly, so the
// global SOURCE is inverse-swizzled (same involution); reads apply the XOR.

__device__ __forceinline__ void stage_tile(const u16* __restrict__ gbase, int ld,
                                           u16* lds_tile, int wid, int lane, int k0) {
    // 128x64 bf16 tile = 16KB = 16 chunks of 1KB; wave wid stages chunks 4*wid..4*wid+3
#pragma unroll
    for (int i = 0; i < 4; ++i) {
        int chunk = wid * 4 + i;
        int row = chunk * 8 + (lane >> 3);
        int pslot = lane & 7;
        const u16* gp = gbase + (size_t)row * ld + k0 + ((pslot ^ (row & 7)) << 3);
        u16* lp = lds_tile + chunk * 512;  // 1KB per chunk, wave-uniform base
        __builtin_amdgcn_global_load_lds((const __attribute__((address_space(1))) void*)gp,
                                         (__attribute__((address_space(3))) void*)lp, 16, 0, 0);
    }
}

__device__ __forceinline__ short8 read_frag(const u16* lds_tile, int row, int ks, int g) {
    int pslot = (ks * 4 + g) ^ (row & 7);
    return *(const short8*)&lds_tile[row * 64 + pslot * 8];
}

// ---------------- QKV GEMM: M=16384, N=1152, K=384 ----------------
__global__ __launch_bounds__(256, 2) void k_gemm_qkv(const u16* __restrict__ xb, const u16* __restrict__ wb,
                                                     u16* __restrict__ q, u16* __restrict__ k,
                                                     u16* __restrict__ v) {
    __shared__ alignas(16) u16 lds[2][16384];  // per buf: A[0..8191] B[8192..16383], 64KB total
    const int tid = threadIdx.x, lane = tid & 63, wid = tid >> 6;
    const int wm = wid >> 1, wn = wid & 1, g = lane >> 4, c = lane & 15;
    const int n0 = blockIdx.x * 128, m0 = blockIdx.y * 128;
    const u16* Ag = xb + (size_t)m0 * 384;
    const u16* Bg = wb + (size_t)n0 * 384;
    f32x4 acc[4][4] = {};
    stage_tile(Ag, 384, &lds[0][0], wid, lane, 0);
    stage_tile(Bg, 384, &lds[0][8192], wid, lane, 0);
    __syncthreads();
    int cur = 0;
    for (int t = 0; t < 6; ++t) {
        if (t < 5) {
            stage_tile(Ag, 384, &lds[cur ^ 1][0], wid, lane, (t + 1) * 64);
            stage_tile(Bg, 384, &lds[cur ^ 1][8192], wid, lane, (t + 1) * 64);
        }
        const u16* A = &lds[cur][0];
        const u16* Bm = &lds[cur][8192];
        short8 af[2][4], bf[2][4];
#pragma unroll
        for (int ks = 0; ks < 2; ++ks) {
#pragma unroll
            for (int mf = 0; mf < 4; ++mf) af[ks][mf] = read_frag(A, wm * 64 + mf * 16 + c, ks, g);
#pragma unroll
            for (int nf = 0; nf < 4; ++nf) bf[ks][nf] = read_frag(Bm, wn * 64 + nf * 16 + c, ks, g);
        }
#pragma unroll
        for (int ks = 0; ks < 2; ++ks)
#pragma unroll
            for (int mf = 0; mf < 4; ++mf)
#pragma unroll
                for (int nf = 0; nf < 4; ++nf)
                    acc[mf][nf] = __builtin_amdgcn_mfma_f32_16x16x32_bf16(af[ks][mf], bf[ks][nf], acc[mf][nf], 0, 0, 0);
        __syncthreads();   // drains vmcnt (next buf staged) + protects cur for restage
        cur ^= 1;
    }
    const int which = n0 / 384;
    u16* dst = (which == 0) ? q : ((which == 1) ? k : v);
    const int h = ((n0 + wn * 64) % 384) / 64;  // wave covers exactly one head
#pragma unroll
    for (int mf = 0; mf < 4; ++mf)
#pragma unroll
        for (int nf = 0; nf < 4; ++nf)
#pragma unroll
            for (int r = 0; r < 4; ++r) {
                int m = m0 + wm * 64 + mf * 16 + g * 4 + r;
                int d = nf * 16 + c;
                int b = m >> 8, t = m & 255;
                dst[((b * H_ + h) * T_ + t) * HD_ + d] = f2bf(acc[mf][nf][r]);
            }
}

// ---------------- fused causal attention (unchanged from passing R0) ----------------
__global__ __launch_bounds__(256, 1) void k_attn(const u16* __restrict__ q, const u16* __restrict__ k,
                                                 const u16* __restrict__ v, u16* __restrict__ ao) {
    __shared__ u16 Kt[64 * 72];        // [s][c] stride 72
    __shared__ u16 Vt[64 * 72];        // transposed: [d][s] stride 72
    __shared__ u16 Ps[4][64 * 72];     // per wave: [q][s] stride 72
    const int tid = threadIdx.x, bh = blockIdx.x;
    const int lane = tid & 63, wid = tid >> 6;
    const int g = lane >> 4, c = lane & 15;
    const int bq = bh * 256;

    short8 qB[4][2];
#pragma unroll
    for (int qf = 0; qf < 4; ++qf)
#pragma unroll
        for (int ks = 0; ks < 2; ++ks) {
            int t = wid * 64 + qf * 16 + c;
            qB[qf][ks] = *(const short8*)&q[(bq + t) * 64 + ks * 32 + g * 8];
        }
    float mrun[4], lrun[4];
#pragma unroll
    for (int i = 0; i < 4; ++i) { mrun[i] = -1e30f; lrun[i] = 0.f; }
    f32x4 o[4][4] = {};

    for (int kt = 0; kt < 4; ++kt) {
#pragma unroll
        for (int i = 0; i < 2; ++i) {
            int idx = tid + i * 256;
            int row = idx >> 3, c8 = (idx & 7) * 8;
            *(short8*)&Kt[row * 72 + c8] = *(const short8*)&k[(bq + kt * 64 + row) * 64 + c8];
            int vrow = idx & 63, vc8 = (idx >> 6) * 8;
            short8 vv = *(const short8*)&v[(bq + kt * 64 + vrow) * 64 + vc8];
#pragma unroll
            for (int j = 0; j < 8; ++j)
                Vt[(vc8 + j) * 72 + vrow] = (u16)vv[j];
        }
        __syncthreads();
        if (kt <= wid) {
            f32x4 st[4][4] = {};
#pragma unroll
            for (int ks = 0; ks < 2; ++ks) {
                short8 kA[4];
#pragma unroll
                for (int sf = 0; sf < 4; ++sf)
                    kA[sf] = *(short8*)&Kt[(sf * 16 + c) * 72 + ks * 32 + g * 8];
#pragma unroll
                for (int sf = 0; sf < 4; ++sf)
#pragma unroll
                    for (int qf = 0; qf < 4; ++qf)
                        st[sf][qf] = __builtin_amdgcn_mfma_f32_16x16x32_bf16(kA[sf], qB[qf][ks], st[sf][qf], 0, 0, 0);
            }
            float pm[4] = {-1e30f, -1e30f, -1e30f, -1e30f};
#pragma unroll
            for (int sf = 0; sf < 4; ++sf)
#pragma unroll
                for (int qf = 0; qf < 4; ++qf)
#pragma unroll
                    for (int r = 0; r < 4; ++r) {
                        float val = st[sf][qf][r] * 0.125f;
                        if (kt == wid) {
                            int s_loc = sf * 16 + g * 4 + r, q_loc = qf * 16 + c;
                            if (s_loc > q_loc) val = -1e30f;
                        }
                        st[sf][qf][r] = val;
                        pm[qf] = fmaxf(pm[qf], val);
                    }
            float alpha[4], lsum[4];
#pragma unroll
            for (int qf = 0; qf < 4; ++qf) {
                pm[qf] = fmaxf(pm[qf], __shfl_xor(pm[qf], 16));
                pm[qf] = fmaxf(pm[qf], __shfl_xor(pm[qf], 32));
                float mnew = fmaxf(mrun[qf], pm[qf]);
                alpha[qf] = __expf(mrun[qf] - mnew);
                mrun[qf] = mnew;
                lsum[qf] = 0.f;
            }
            u16* myPs = Ps[wid];
#pragma unroll
            for (int sf = 0; sf < 4; ++sf)
#pragma unroll
                for (int qf = 0; qf < 4; ++qf) {
                    short4_ pb;
                    float s4 = 0.f;
#pragma unroll
                    for (int r = 0; r < 4; ++r) {
                        float p = __expf(st[sf][qf][r] - mrun[qf]);
                        s4 += p;
                        pb[r] = (short)f2bf(p);
                    }
                    lsum[qf] += s4;
                    *(short4_*)&myPs[(qf * 16 + c) * 72 + sf * 16 + g * 4] = pb;
                }
#pragma unroll
            for (int qf = 0; qf < 4; ++qf) {
                lsum[qf] += __shfl_xor(lsum[qf], 16);
                lsum[qf] += __shfl_xor(lsum[qf], 32);
                lrun[qf] = lrun[qf] * alpha[qf] + lsum[qf];
            }
#pragma unroll
            for (int mf = 0; mf < 4; ++mf)
#pragma unroll
                for (int r = 0; r < 4; ++r) {
                    float aof = __shfl(alpha[mf], g * 4 + r);
#pragma unroll
                    for (int df = 0; df < 4; ++df)
                        o[mf][df][r] *= aof;
                }
#pragma unroll
            for (int ks = 0; ks < 2; ++ks) {
                short8 vB[4], pA[4];
#pragma unroll
                for (int df = 0; df < 4; ++df)
                    vB[df] = *(short8*)&Vt[(df * 16 + c) * 72 + ks * 32 + g * 8];
#pragma unroll
                for (int mf = 0; mf < 4; ++mf)
                    pA[mf] = *(short8*)&myPs[(mf * 16 + c) * 72 + ks * 32 + g * 8];
#pragma unroll
                for (int mf = 0; mf < 4; ++mf)
#pragma unroll
                    for (int df = 0; df < 4; ++df)
                        o[mf][df] = __builtin_amdgcn_mfma_f32_16x16x32_bf16(pA[mf], vB[df], o[mf][df], 0, 0, 0);
            }
        }
        __syncthreads();
    }
    const int bb = bh / H_, hh = bh % H_;
#pragma unroll
    for (int mf = 0; mf < 4; ++mf)
#pragma unroll
        for (int r = 0; r < 4; ++r) {
            float inv = 1.0f / __shfl(lrun[mf], g * 4 + r);
            int t = wid * 64 + mf * 16 + g * 4 + r;
#pragma unroll
            for (int df = 0; df < 4; ++df) {
                int d = df * 16 + c;
                ao[((size_t)(bb * T_ + t)) * C_ + hh * 64 + d] = f2bf(o[mf][df][r] * inv);
            }
        }
}

// ---------------- output projection: M=16384, N=384, K=384, + bias, fp32 out ----------------
__global__ __launch_bounds__(256, 2) void k_gemm_proj(const u16* __restrict__ ab, const u16* __restrict__ wp,
                                                      const float* __restrict__ bp, float* __restrict__ out) {
    __shared__ alignas(16) u16 lds[2][16384];
    const int tid = threadIdx.x, lane = tid & 63, wid = tid >> 6;
    const int wm = wid >> 1, wn = wid & 1, g = lane >> 4, c = lane & 15;
    const int n0 = blockIdx.x * 128, m0 = blockIdx.y * 128;
    const u16* Ag = ab + (size_t)m0 * 384;
    const u16* Bg = wp + (size_t)n0 * 384;
    f32x4 acc[4][4] = {};
    stage_tile(Ag, 384, &lds[0][0], wid, lane, 0);
    stage_tile(Bg, 384, &lds[0][8192], wid, lane, 0);
    __syncthreads();
    int cur = 0;
    for (int t = 0; t < 6; ++t) {
        if (t < 5) {
            stage_tile(Ag, 384, &lds[cur ^ 1][0], wid, lane, (t + 1) * 64);
            stage_tile(Bg, 384, &lds[cur ^ 1][8192], wid, lane, (t + 1) * 64);
        }
        const u16* A = &lds[cur][0];
        const u16* Bm = &lds[cur][8192];
        short8 af[2][4], bf[2][4];
#pragma unroll
        for (int ks = 0; ks < 2; ++ks) {
#pragma unroll
            for (int mf = 0; mf < 4; ++mf) af[ks][mf] = read_frag(A, wm * 64 + mf * 16 + c, ks, g);
#pragma unroll
            for (int nf = 0; nf < 4; ++nf) bf[ks][nf] = read_frag(Bm, wn * 64 + nf * 16 + c, ks, g);
        }
#pragma unroll
        for (int ks = 0; ks < 2; ++ks)
#pragma unroll
            for (int mf = 0; mf < 4; ++mf)
#pragma unroll
                for (int nf = 0; nf < 4; ++nf)
                    acc[mf][nf] = __builtin_amdgcn_mfma_f32_16x16x32_bf16(af[ks][mf], bf[ks][nf], acc[mf][nf], 0, 0, 0);
        __syncthreads();
        cur ^= 1;
    }
#pragma unroll
    for (int mf = 0; mf < 4; ++mf)
#pragma unroll
        for (int nf = 0; nf < 4; ++nf)
#pragma unroll
            for (int r = 0; r < 4; ++r) {
                int m = m0 + wm * 64 + mf * 16 + g * 4 + r;
                int n = n0 + wn * 64 + nf * 16 + c;
                out[(size_t)m * C_ + n] = acc[mf][nf][r] + bp[n];
            }
}

// ---------------- host ----------------

extern "C" void kernel_launch(void* const* d_in, const int* in_sizes, int n_in,
                              void* d_out, int out_size, void* d_ws, size_t ws_size,
                              hipStream_t stream) {
    const float* x  = (const float*)d_in[0];
    const float* Wq = (const float*)d_in[1];
    const float* Wk = (const float*)d_in[2];
    const float* Wv = (const float*)d_in[3];
    const float* Wp = (const float*)d_in[4];
    const float* bp = (const float*)d_in[5];
    float* out = (float*)d_out;

    char* ws = (char*)d_ws;
    u16* xb   = (u16*)(ws);                    // 16384*384 bf16
    u16* wqkv = (u16*)(ws + 12582912);         // 1152*384
    u16* wpb  = (u16*)(ws + 13467648);         // 384*384
    u16* qb   = (u16*)(ws + 13762560);         // 64*6*256*64
    u16* kb   = (u16*)(ws + 26345472);
    u16* vb   = (u16*)(ws + 38928384);
    u16* ab   = (u16*)(ws + 51511296);         // 16384*384 bf16

    k_prep<<<4872, 256, 0, stream>>>(x, Wq, Wk, Wv, Wp, xb, wqkv, wpb);
    k_gemm_qkv<<<dim3(9, 128), 256, 0, stream>>>(xb, wqkv, qb, kb, vb);
    k_attn<<<384, 256, 0, stream>>>(qb, kb, vb, ab);
    k_gemm_proj<<<dim3(3, 128), 256, 0, stream>>>(ab, wpb, bp, out);
}

// Round 3
// 74.123 us; speedup vs baseline: 1.3482x; 1.1559x over previous
//
#include <hip/hip_runtime.h>
#include <hip/hip_bf16.h>
#include <cstdint>
#include <cstddef>

#define B_ 64
#define T_ 256
#define C_ 384
#define H_ 6
#define HD_ 64

using u16 = unsigned short;
typedef __attribute__((ext_vector_type(8))) short short8;   // 8 bf16 (4 VGPR)
typedef __attribute__((ext_vector_type(4))) short short4_;  // 4 bf16 (8 B)
typedef __attribute__((ext_vector_type(4))) float f32x4;

__device__ __forceinline__ u16 f2bf(float f) {
    union { float f; uint32_t u; } x{f};
    uint32_t r = x.u + 0x7fffu + ((x.u >> 16) & 1u);
    return (u16)(r >> 16);
}

// ---------------- fused prep: cvt x, pack Wqkv (LDS transpose), cvt Wp ----------------
// blocks [0,3072): x -> xb (8 elems/thread)
// blocks [3072,3180): pack Wq/Wk/Wv -> wqkv [1152][384] n-major, coalesced both sides
// blocks [3180,3252): Wp -> wpb
__global__ void k_prep(const float* __restrict__ x, const float* __restrict__ Wq,
                       const float* __restrict__ Wk, const float* __restrict__ Wv,
                       const float* __restrict__ Wp, u16* __restrict__ xb,
                       u16* __restrict__ wqkv, u16* __restrict__ wpb) {
    int bid = blockIdx.x;
    if (bid < 3072) {
        int i = (bid * 256 + threadIdx.x) * 8;
        const f32x4* p = (const f32x4*)(x + i);
        f32x4 a = p[0], b = p[1];
        short8 s;
        s[0] = (short)f2bf(a[0]); s[1] = (short)f2bf(a[1]);
        s[2] = (short)f2bf(a[2]); s[3] = (short)f2bf(a[3]);
        s[4] = (short)f2bf(b[0]); s[5] = (short)f2bf(b[1]);
        s[6] = (short)f2bf(b[2]); s[7] = (short)f2bf(b[3]);
        *(short8*)(xb + i) = s;
    } else if (bid < 3180) {
        // transpose-pack one 64cc x 64d tile of W_which[h]
        __shared__ u16 Tt[64 * 65];
        int pb = bid - 3072;
        int which = pb / 36, rem = pb % 36;
        int h = rem / 6, cc0 = (rem % 6) * 64;
        const float* W = (which == 0) ? Wq : ((which == 1) ? Wk : Wv);
        int d = threadIdx.x & 63, cr0 = threadIdx.x >> 6;
#pragma unroll
        for (int p = 0; p < 16; ++p) {
            int cr = p * 4 + cr0;
            Tt[cr * 65 + d] = f2bf(W[(h * 384 + cc0 + cr) * 64 + d]);  // 256B coalesced read
        }
        __syncthreads();
        int ccl = threadIdx.x & 63, dl0 = threadIdx.x >> 6;
        int nbase = which * 384 + h * 64;
#pragma unroll
        for (int p = 0; p < 16; ++p) {
            int dl = p * 4 + dl0;
            wqkv[(size_t)(nbase + dl) * 384 + cc0 + ccl] = Tt[ccl * 65 + dl];  // 128B coalesced write
        }
    } else {
        int i = ((bid - 3180) * 256 + threadIdx.x) * 8;
        const f32x4* p = (const f32x4*)(Wp + i);
        f32x4 a = p[0], b = p[1];
        short8 s;
        s[0] = (short)f2bf(a[0]); s[1] = (short)f2bf(a[1]);
        s[2] = (short)f2bf(a[2]); s[3] = (short)f2bf(a[3]);
        s[4] = (short)f2bf(b[0]); s[5] = (short)f2bf(b[1]);
        s[6] = (short)f2bf(b[2]); s[7] = (short)f2bf(b[3]);
        *(short8*)(wpb + i) = s;
    }
}

// ---------------- GEMM core: 128x128 tile, BK=64, global_load_lds + swizzle ----------------
__device__ __forceinline__ void stage_tile(const u16* __restrict__ gbase, int ld,
                                           u16* lds_tile, int wid, int lane, int k0) {
#pragma unroll
    for (int i = 0; i < 4; ++i) {
        int chunk = wid * 4 + i;
        int row = chunk * 8 + (lane >> 3);
        int pslot = lane & 7;
        const u16* gp = gbase + (size_t)row * ld + k0 + ((pslot ^ (row & 7)) << 3);
        u16* lp = lds_tile + chunk * 512;
        __builtin_amdgcn_global_load_lds((const __attribute__((address_space(1))) void*)gp,
                                         (__attribute__((address_space(3))) void*)lp, 16, 0, 0);
    }
}

__device__ __forceinline__ short8 read_frag(const u16* lds_tile, int row, int ks, int g) {
    int pslot = (ks * 4 + g) ^ (row & 7);
    return *(const short8*)&lds_tile[row * 64 + pslot * 8];
}

// ---------------- QKV GEMM: M=16384, N=1152, K=384 ----------------
__global__ __launch_bounds__(256, 2) void k_gemm_qkv(const u16* __restrict__ xb, const u16* __restrict__ wb,
                                                     u16* __restrict__ q, u16* __restrict__ k,
                                                     u16* __restrict__ v) {
    __shared__ alignas(16) u16 lds[2][16384];
    const int tid = threadIdx.x, lane = tid & 63, wid = tid >> 6;
    const int wm = wid >> 1, wn = wid & 1, g = lane >> 4, c = lane & 15;
    const int n0 = blockIdx.x * 128, m0 = blockIdx.y * 128;
    const u16* Ag = xb + (size_t)m0 * 384;
    const u16* Bg = wb + (size_t)n0 * 384;
    f32x4 acc[4][4] = {};
    stage_tile(Ag, 384, &lds[0][0], wid, lane, 0);
    stage_tile(Bg, 384, &lds[0][8192], wid, lane, 0);
    __syncthreads();
    int cur = 0;
    for (int t = 0; t < 6; ++t) {
        if (t < 5) {
            stage_tile(Ag, 384, &lds[cur ^ 1][0], wid, lane, (t + 1) * 64);
            stage_tile(Bg, 384, &lds[cur ^ 1][8192], wid, lane, (t + 1) * 64);
        }
        const u16* A = &lds[cur][0];
        const u16* Bm = &lds[cur][8192];
        short8 af[2][4], bf[2][4];
#pragma unroll
        for (int ks = 0; ks < 2; ++ks) {
#pragma unroll
            for (int mf = 0; mf < 4; ++mf) af[ks][mf] = read_frag(A, wm * 64 + mf * 16 + c, ks, g);
#pragma unroll
            for (int nf = 0; nf < 4; ++nf) bf[ks][nf] = read_frag(Bm, wn * 64 + nf * 16 + c, ks, g);
        }
#pragma unroll
        for (int ks = 0; ks < 2; ++ks)
#pragma unroll
            for (int mf = 0; mf < 4; ++mf)
#pragma unroll
                for (int nf = 0; nf < 4; ++nf)
                    acc[mf][nf] = __builtin_amdgcn_mfma_f32_16x16x32_bf16(af[ks][mf], bf[ks][nf], acc[mf][nf], 0, 0, 0);
        __syncthreads();
        cur ^= 1;
    }
    const int which = n0 / 384;
    u16* dst = (which == 0) ? q : ((which == 1) ? k : v);
    const int h = ((n0 + wn * 64) % 384) / 64;
#pragma unroll
    for (int mf = 0; mf < 4; ++mf)
#pragma unroll
        for (int nf = 0; nf < 4; ++nf)
#pragma unroll
            for (int r = 0; r < 4; ++r) {
                int m = m0 + wm * 64 + mf * 16 + g * 4 + r;
                int d = nf * 16 + c;
                int b = m >> 8, t = m & 255;
                dst[((b * H_ + h) * T_ + t) * HD_ + d] = f2bf(acc[mf][nf][r]);
            }
}

// ---------------- fused causal attention: in-register P, permuted-V PV ----------------
// Swapped QK^T: lane (c,g) holds S[q=c][s=sf*16+4g+r] in st[sf][qf][r].
// PV A-frag k-slot kappa = ks*32 + g*8 + e maps to s(kappa) = 32ks + 16*(e>>2) + 4g + (e&3);
// V is staged with column kappa(s) = 32(s>>5) + 8((s>>2)&3) + 4((s>>4)&1) + (s&3),
// so pA is a pure in-register repack of st and no P LDS/shuffle is needed.
__global__ __launch_bounds__(256, 2) void k_attn(const u16* __restrict__ q, const u16* __restrict__ k,
                                                 const u16* __restrict__ v, u16* __restrict__ ao) {
    __shared__ u16 Kt[64 * 72];        // [s][c] stride 72
    __shared__ u16 Vt[64 * 72];        // [d][kappa] stride 72
    const int tid = threadIdx.x, bh = blockIdx.x;
    const int lane = tid & 63, wid = tid >> 6;
    const int g = lane >> 4, c = lane & 15;
    const int bq = bh * 256;

    short8 qB[4][2];
#pragma unroll
    for (int qf = 0; qf < 4; ++qf)
#pragma unroll
        for (int ks = 0; ks < 2; ++ks) {
            int t = wid * 64 + qf * 16 + c;
            qB[qf][ks] = *(const short8*)&q[(bq + t) * 64 + ks * 32 + g * 8];
        }
    float mrun[4], lrun[4];
#pragma unroll
    for (int i = 0; i < 4; ++i) { mrun[i] = -1e30f; lrun[i] = 0.f; }
    f32x4 o[4][4] = {};

    for (int kt = 0; kt < 4; ++kt) {
#pragma unroll
        for (int i = 0; i < 2; ++i) {
            int idx = tid + i * 256;
            int row = idx >> 3, c8 = (idx & 7) * 8;
            *(short8*)&Kt[row * 72 + c8] = *(const short8*)&k[(bq + kt * 64 + row) * 64 + c8];
            int vrow = idx & 63, vc8 = (idx >> 6) * 8;
            int kv = ((vrow >> 5) << 5) | (((vrow >> 2) & 3) << 3) | (((vrow >> 4) & 1) << 2) | (vrow & 3);
            short8 vv = *(const short8*)&v[(bq + kt * 64 + vrow) * 64 + vc8];
#pragma unroll
            for (int j = 0; j < 8; ++j)
                Vt[(vc8 + j) * 72 + kv] = (u16)vv[j];
        }
        __syncthreads();
        if (kt <= wid) {
            f32x4 st[4][4] = {};
#pragma unroll
            for (int ks = 0; ks < 2; ++ks) {
                short8 kA[4];
#pragma unroll
                for (int sf = 0; sf < 4; ++sf)
                    kA[sf] = *(short8*)&Kt[(sf * 16 + c) * 72 + ks * 32 + g * 8];
#pragma unroll
                for (int sf = 0; sf < 4; ++sf)
#pragma unroll
                    for (int qf = 0; qf < 4; ++qf)
                        st[sf][qf] = __builtin_amdgcn_mfma_f32_16x16x32_bf16(kA[sf], qB[qf][ks], st[sf][qf], 0, 0, 0);
            }
            float pm[4] = {-1e30f, -1e30f, -1e30f, -1e30f};
#pragma unroll
            for (int sf = 0; sf < 4; ++sf)
#pragma unroll
                for (int qf = 0; qf < 4; ++qf)
#pragma unroll
                    for (int r = 0; r < 4; ++r) {
                        float val = st[sf][qf][r] * 0.125f;
                        if (kt == wid) {
                            int s_loc = sf * 16 + g * 4 + r, q_loc = qf * 16 + c;
                            if (s_loc > q_loc) val = -1e30f;
                        }
                        st[sf][qf][r] = val;
                        pm[qf] = fmaxf(pm[qf], val);
                    }
            float alpha[4];
#pragma unroll
            for (int qf = 0; qf < 4; ++qf) {
                pm[qf] = fmaxf(pm[qf], __shfl_xor(pm[qf], 16));
                pm[qf] = fmaxf(pm[qf], __shfl_xor(pm[qf], 32));
                float mnew = fmaxf(mrun[qf], pm[qf]);
                alpha[qf] = __expf(mrun[qf] - mnew);
                mrun[qf] = mnew;
            }
            // exp + pack P into A-fragments entirely in registers
            short8 pA[4][2];
#pragma unroll
            for (int qf = 0; qf < 4; ++qf) {
                float ls = 0.f;
#pragma unroll
                for (int ks = 0; ks < 2; ++ks) {
                    short8 pa;
#pragma unroll
                    for (int half = 0; half < 2; ++half) {
                        f32x4 sv = st[2 * ks + half][qf];
#pragma unroll
                        for (int r = 0; r < 4; ++r) {
                            float p = __expf(sv[r] - mrun[qf]);
                            ls += p;
                            pa[half * 4 + r] = (short)f2bf(p);
                        }
                    }
                    pA[qf][ks] = pa;
                }
                ls += __shfl_xor(ls, 16);
                ls += __shfl_xor(ls, 32);
                lrun[qf] = lrun[qf] * alpha[qf] + ls;
            }
            // rescale O
#pragma unroll
            for (int mf = 0; mf < 4; ++mf)
#pragma unroll
                for (int r = 0; r < 4; ++r) {
                    float aof = __shfl(alpha[mf], g * 4 + r);
#pragma unroll
                    for (int df = 0; df < 4; ++df)
                        o[mf][df][r] *= aof;
                }
            // PV with permuted-V B-frags
#pragma unroll
            for (int ks = 0; ks < 2; ++ks) {
                short8 vB[4];
#pragma unroll
                for (int df = 0; df < 4; ++df)
                    vB[df] = *(short8*)&Vt[(df * 16 + c) * 72 + ks * 32 + g * 8];
#pragma unroll
                for (int mf = 0; mf < 4; ++mf)
#pragma unroll
                    for (int df = 0; df < 4; ++df)
                        o[mf][df] = __builtin_amdgcn_mfma_f32_16x16x32_bf16(pA[mf][ks], vB[df], o[mf][df], 0, 0, 0);
            }
        }
        __syncthreads();
    }
    const int bb = bh / H_, hh = bh % H_;
#pragma unroll
    for (int mf = 0; mf < 4; ++mf)
#pragma unroll
        for (int r = 0; r < 4; ++r) {
            float inv = 1.0f / __shfl(lrun[mf], g * 4 + r);
            int t = wid * 64 + mf * 16 + g * 4 + r;
#pragma unroll
            for (int df = 0; df < 4; ++df) {
                int d = df * 16 + c;
                ao[((size_t)(bb * T_ + t)) * C_ + hh * 64 + d] = f2bf(o[mf][df][r] * inv);
            }
        }
}

// ---------------- output projection: M=16384, N=384, K=384, + bias, fp32 out ----------------
__global__ __launch_bounds__(256, 2) void k_gemm_proj(const u16* __restrict__ ab, const u16* __restrict__ wp,
                                                      const float* __restrict__ bp, float* __restrict__ out) {
    __shared__ alignas(16) u16 lds[2][16384];
    const int tid = threadIdx.x, lane = tid & 63, wid = tid >> 6;
    const int wm = wid >> 1, wn = wid & 1, g = lane >> 4, c = lane & 15;
    const int n0 = blockIdx.x * 128, m0 = blockIdx.y * 128;
    const u16* Ag = ab + (size_t)m0 * 384;
    const u16* Bg = wp + (size_t)n0 * 384;
    f32x4 acc[4][4] = {};
    stage_tile(Ag, 384, &lds[0][0], wid, lane, 0);
    stage_tile(Bg, 384, &lds[0][8192], wid, lane, 0);
    __syncthreads();
    int cur = 0;
    for (int t = 0; t < 6; ++t) {
        if (t < 5) {
            stage_tile(Ag, 384, &lds[cur ^ 1][0], wid, lane, (t + 1) * 64);
            stage_tile(Bg, 384, &lds[cur ^ 1][8192], wid, lane, (t + 1) * 64);
        }
        const u16* A = &lds[cur][0];
        const u16* Bm = &lds[cur][8192];
        short8 af[2][4], bf[2][4];
#pragma unroll
        for (int ks = 0; ks < 2; ++ks) {
#pragma unroll
            for (int mf = 0; mf < 4; ++mf) af[ks][mf] = read_frag(A, wm * 64 + mf * 16 + c, ks, g);
#pragma unroll
            for (int nf = 0; nf < 4; ++nf) bf[ks][nf] = read_frag(Bm, wn * 64 + nf * 16 + c, ks, g);
        }
#pragma unroll
        for (int ks = 0; ks < 2; ++ks)
#pragma unroll
            for (int mf = 0; mf < 4; ++mf)
#pragma unroll
                for (int nf = 0; nf < 4; ++nf)
                    acc[mf][nf] = __builtin_amdgcn_mfma_f32_16x16x32_bf16(af[ks][mf], bf[ks][nf], acc[mf][nf], 0, 0, 0);
        __syncthreads();
        cur ^= 1;
    }
#pragma unroll
    for (int mf = 0; mf < 4; ++mf)
#pragma unroll
        for (int nf = 0; nf < 4; ++nf)
#pragma unroll
            for (int r = 0; r < 4; ++r) {
                int m = m0 + wm * 64 + mf * 16 + g * 4 + r;
                int n = n0 + wn * 64 + nf * 16 + c;
                out[(size_t)m * C_ + n] = acc[mf][nf][r] + bp[n];
            }
}

// ---------------- host ----------------

extern "C" void kernel_launch(void* const* d_in, const int* in_sizes, int n_in,
                              void* d_out, int out_size, void* d_ws, size_t ws_size,
                              hipStream_t stream) {
    const float* x  = (const float*)d_in[0];
    const float* Wq = (const float*)d_in[1];
    const float* Wk = (const float*)d_in[2];
    const float* Wv = (const float*)d_in[3];
    const float* Wp = (const float*)d_in[4];
    const float* bp = (const float*)d_in[5];
    float* out = (float*)d_out;

    char* ws = (char*)d_ws;
    u16* xb   = (u16*)(ws);                    // 16384*384 bf16
    u16* wqkv = (u16*)(ws + 12582912);         // 1152*384
    u16* wpb  = (u16*)(ws + 13467648);         // 384*384
    u16* qb   = (u16*)(ws + 13762560);         // 64*6*256*64
    u16* kb   = (u16*)(ws + 26345472);
    u16* vb   = (u16*)(ws + 38928384);
    u16* ab   = (u16*)(ws + 51511296);         // 16384*384 bf16

    k_prep<<<3252, 256, 0, stream>>>(x, Wq, Wk, Wv, Wp, xb, wqkv, wpb);
    k_gemm_qkv<<<dim3(9, 128), 256, 0, stream>>>(xb, wqkv, qb, kb, vb);
    k_attn<<<384, 256, 0, stream>>>(qb, kb, vb, ab);
    k_gemm_proj<<<dim3(3, 128), 256, 0, stream>>>(ab, wpb, bp, out);
}

// Round 4
// 74.091 us; speedup vs baseline: 1.3488x; 1.0004x over previous
//
#include <hip/hip_runtime.h>
#include <hip/hip_bf16.h>
#include <cstdint>
#include <cstddef>

#define B_ 64
#define T_ 256
#define C_ 384
#define H_ 6
#define HD_ 64

using u16 = unsigned short;
typedef __attribute__((ext_vector_type(8))) short short8;   // 8 bf16 (4 VGPR)
typedef __attribute__((ext_vector_type(4))) short short4_;  // 4 bf16 (8 B)
typedef __attribute__((ext_vector_type(4))) float f32x4;

__device__ __forceinline__ u16 f2bf(float f) {
    union { float f; uint32_t u; } x{f};
    uint32_t r = x.u + 0x7fffu + ((x.u >> 16) & 1u);
    return (u16)(r >> 16);
}

// ---------------- fused prep: cvt x, pack Wqkv (LDS transpose), cvt Wp ----------------
__global__ void k_prep(const float* __restrict__ x, const float* __restrict__ Wq,
                       const float* __restrict__ Wk, const float* __restrict__ Wv,
                       const float* __restrict__ Wp, u16* __restrict__ xb,
                       u16* __restrict__ wqkv, u16* __restrict__ wpb) {
    int bid = blockIdx.x;
    if (bid < 3072) {
        int i = (bid * 256 + threadIdx.x) * 8;
        const f32x4* p = (const f32x4*)(x + i);
        f32x4 a = p[0], b = p[1];
        short8 s;
        s[0] = (short)f2bf(a[0]); s[1] = (short)f2bf(a[1]);
        s[2] = (short)f2bf(a[2]); s[3] = (short)f2bf(a[3]);
        s[4] = (short)f2bf(b[0]); s[5] = (short)f2bf(b[1]);
        s[6] = (short)f2bf(b[2]); s[7] = (short)f2bf(b[3]);
        *(short8*)(xb + i) = s;
    } else if (bid < 3180) {
        __shared__ u16 Tt[64 * 65];
        int pb = bid - 3072;
        int which = pb / 36, rem = pb % 36;
        int h = rem / 6, cc0 = (rem % 6) * 64;
        const float* W = (which == 0) ? Wq : ((which == 1) ? Wk : Wv);
        int d = threadIdx.x & 63, cr0 = threadIdx.x >> 6;
#pragma unroll
        for (int p = 0; p < 16; ++p) {
            int cr = p * 4 + cr0;
            Tt[cr * 65 + d] = f2bf(W[(h * 384 + cc0 + cr) * 64 + d]);
        }
        __syncthreads();
        int ccl = threadIdx.x & 63, dl0 = threadIdx.x >> 6;
        int nbase = which * 384 + h * 64;
#pragma unroll
        for (int p = 0; p < 16; ++p) {
            int dl = p * 4 + dl0;
            wqkv[(size_t)(nbase + dl) * 384 + cc0 + ccl] = Tt[ccl * 65 + dl];
        }
    } else {
        int i = ((bid - 3180) * 256 + threadIdx.x) * 8;
        const f32x4* p = (const f32x4*)(Wp + i);
        f32x4 a = p[0], b = p[1];
        short8 s;
        s[0] = (short)f2bf(a[0]); s[1] = (short)f2bf(a[1]);
        s[2] = (short)f2bf(a[2]); s[3] = (short)f2bf(a[3]);
        s[4] = (short)f2bf(b[0]); s[5] = (short)f2bf(b[1]);
        s[6] = (short)f2bf(b[2]); s[7] = (short)f2bf(b[3]);
        *(short8*)(wpb + i) = s;
    }
}

// ---------------- GEMM core helpers ----------------
__device__ __forceinline__ void stage_tile(const u16* __restrict__ gbase, int ld,
                                           u16* lds_tile, int wid, int lane, int k0) {
#pragma unroll
    for (int i = 0; i < 4; ++i) {
        int chunk = wid * 4 + i;
        int row = chunk * 8 + (lane >> 3);
        int pslot = lane & 7;
        const u16* gp = gbase + (size_t)row * ld + k0 + ((pslot ^ (row & 7)) << 3);
        u16* lp = lds_tile + chunk * 512;
        __builtin_amdgcn_global_load_lds((const __attribute__((address_space(1))) void*)gp,
                                         (__attribute__((address_space(3))) void*)lp, 16, 0, 0);
    }
}

__device__ __forceinline__ short8 read_frag(const u16* lds_tile, int row, int ks, int g) {
    int pslot = (ks * 4 + g) ^ (row & 7);
    return *(const short8*)&lds_tile[row * 64 + pslot * 8];
}

// Counted-vmcnt 2-deep pipeline body shared by both GEMMs (T3-min + T4).
// Per step: issue 8 gload_lds for t+1, waitcnt vmcnt(8) (drains only tile t),
// barrier, frag-read+MFMA, barrier. Loads for t+1 stay in flight across MFMA.
#define GEMM_PIPE_LOOP(NT)                                                        \
    int cur = 0;                                                                  \
    for (int t = 0; t < (NT); ++t) {                                              \
        if (t < (NT) - 1) {                                                       \
            stage_tile(Ag, 384, &lds[cur ^ 1][0], wid, lane, (t + 1) * 64);       \
            stage_tile(Bg, 384, &lds[cur ^ 1][8192], wid, lane, (t + 1) * 64);    \
            asm volatile("s_waitcnt vmcnt(8)" ::: "memory");                      \
        } else {                                                                  \
            asm volatile("s_waitcnt vmcnt(0)" ::: "memory");                      \
        }                                                                         \
        __builtin_amdgcn_s_barrier();                                             \
        __builtin_amdgcn_sched_barrier(0);                                        \
        const u16* A = &lds[cur][0];                                              \
        const u16* Bm = &lds[cur][8192];                                          \
        short8 af[2][4], bf[2][4];                                                \
        _Pragma("unroll")                                                         \
        for (int ks = 0; ks < 2; ++ks) {                                          \
            _Pragma("unroll")                                                     \
            for (int mf = 0; mf < 4; ++mf) af[ks][mf] = read_frag(A, wm * 64 + mf * 16 + c, ks, g); \
            _Pragma("unroll")                                                     \
            for (int nf = 0; nf < 4; ++nf) bf[ks][nf] = read_frag(Bm, wn * 64 + nf * 16 + c, ks, g); \
        }                                                                         \
        _Pragma("unroll")                                                         \
        for (int ks = 0; ks < 2; ++ks)                                            \
            _Pragma("unroll")                                                     \
            for (int mf = 0; mf < 4; ++mf)                                        \
                _Pragma("unroll")                                                 \
                for (int nf = 0; nf < 4; ++nf)                                    \
                    acc[mf][nf] = __builtin_amdgcn_mfma_f32_16x16x32_bf16(af[ks][mf], bf[ks][nf], acc[mf][nf], 0, 0, 0); \
        __builtin_amdgcn_sched_barrier(0);                                        \
        __builtin_amdgcn_s_barrier();                                             \
        cur ^= 1;                                                                 \
    }

// ---------------- QKV GEMM: M=16384, N=1152, K=384 ----------------
__global__ __launch_bounds__(256, 2) void k_gemm_qkv(const u16* __restrict__ xb, const u16* __restrict__ wb,
                                                     u16* __restrict__ q, u16* __restrict__ k,
                                                     u16* __restrict__ v) {
    __shared__ alignas(16) u16 lds[2][16384];
    const int tid = threadIdx.x, lane = tid & 63, wid = tid >> 6;
    const int wm = wid >> 1, wn = wid & 1, g = lane >> 4, c = lane & 15;
    const int n0 = blockIdx.x * 128, m0 = blockIdx.y * 128;
    const u16* Ag = xb + (size_t)m0 * 384;
    const u16* Bg = wb + (size_t)n0 * 384;
    f32x4 acc[4][4] = {};
    stage_tile(Ag, 384, &lds[0][0], wid, lane, 0);
    stage_tile(Bg, 384, &lds[0][8192], wid, lane, 0);
    GEMM_PIPE_LOOP(6)
    const int which = n0 / 384;
    u16* dst = (which == 0) ? q : ((which == 1) ? k : v);
    const int h = ((n0 + wn * 64) % 384) / 64;
#pragma unroll
    for (int mf = 0; mf < 4; ++mf)
#pragma unroll
        for (int nf = 0; nf < 4; ++nf)
#pragma unroll
            for (int r = 0; r < 4; ++r) {
                int m = m0 + wm * 64 + mf * 16 + g * 4 + r;
                int d = nf * 16 + c;
                int b = m >> 8, t = m & 255;
                dst[((b * H_ + h) * T_ + t) * HD_ + d] = f2bf(acc[mf][nf][r]);
            }
}

// ---------------- fused causal attention: in-register P, permuted-V PV ----------------
__global__ __launch_bounds__(256, 2) void k_attn(const u16* __restrict__ q, const u16* __restrict__ k,
                                                 const u16* __restrict__ v, u16* __restrict__ ao) {
    __shared__ u16 Kt[64 * 72];        // [s][c] stride 72
    __shared__ u16 Vt[64 * 72];        // [d][kappa] stride 72
    const int tid = threadIdx.x, bh = blockIdx.x;
    const int lane = tid & 63, wid = tid >> 6;
    const int g = lane >> 4, c = lane & 15;
    const int bq = bh * 256;

    short8 qB[4][2];
#pragma unroll
    for (int qf = 0; qf < 4; ++qf)
#pragma unroll
        for (int ks = 0; ks < 2; ++ks) {
            int t = wid * 64 + qf * 16 + c;
            qB[qf][ks] = *(const short8*)&q[(bq + t) * 64 + ks * 32 + g * 8];
        }
    float mrun[4], lrun[4];
#pragma unroll
    for (int i = 0; i < 4; ++i) { mrun[i] = -1e30f; lrun[i] = 0.f; }
    f32x4 o[4][4] = {};

    for (int kt = 0; kt < 4; ++kt) {
#pragma unroll
        for (int i = 0; i < 2; ++i) {
            int idx = tid + i * 256;
            int row = idx >> 3, c8 = (idx & 7) * 8;
            *(short8*)&Kt[row * 72 + c8] = *(const short8*)&k[(bq + kt * 64 + row) * 64 + c8];
            int vrow = idx & 63, vc8 = (idx >> 6) * 8;
            int kv = ((vrow >> 5) << 5) | (((vrow >> 2) & 3) << 3) | (((vrow >> 4) & 1) << 2) | (vrow & 3);
            short8 vv = *(const short8*)&v[(bq + kt * 64 + vrow) * 64 + vc8];
#pragma unroll
            for (int j = 0; j < 8; ++j)
                Vt[(vc8 + j) * 72 + kv] = (u16)vv[j];
        }
        __syncthreads();
        if (kt <= wid) {
            f32x4 st[4][4] = {};
#pragma unroll
            for (int ks = 0; ks < 2; ++ks) {
                short8 kA[4];
#pragma unroll
                for (int sf = 0; sf < 4; ++sf)
                    kA[sf] = *(short8*)&Kt[(sf * 16 + c) * 72 + ks * 32 + g * 8];
#pragma unroll
                for (int sf = 0; sf < 4; ++sf)
#pragma unroll
                    for (int qf = 0; qf < 4; ++qf)
                        st[sf][qf] = __builtin_amdgcn_mfma_f32_16x16x32_bf16(kA[sf], qB[qf][ks], st[sf][qf], 0, 0, 0);
            }
            float pm[4] = {-1e30f, -1e30f, -1e30f, -1e30f};
#pragma unroll
            for (int sf = 0; sf < 4; ++sf)
#pragma unroll
                for (int qf = 0; qf < 4; ++qf)
#pragma unroll
                    for (int r = 0; r < 4; ++r) {
                        float val = st[sf][qf][r] * 0.125f;
                        if (kt == wid) {
                            int s_loc = sf * 16 + g * 4 + r, q_loc = qf * 16 + c;
                            if (s_loc > q_loc) val = -1e30f;
                        }
                        st[sf][qf][r] = val;
                        pm[qf] = fmaxf(pm[qf], val);
                    }
            float alpha[4];
#pragma unroll
            for (int qf = 0; qf < 4; ++qf) {
                pm[qf] = fmaxf(pm[qf], __shfl_xor(pm[qf], 16));
                pm[qf] = fmaxf(pm[qf], __shfl_xor(pm[qf], 32));
                float mnew = fmaxf(mrun[qf], pm[qf]);
                alpha[qf] = __expf(mrun[qf] - mnew);
                mrun[qf] = mnew;
            }
            short8 pA[4][2];
#pragma unroll
            for (int qf = 0; qf < 4; ++qf) {
                float ls = 0.f;
#pragma unroll
                for (int ks = 0; ks < 2; ++ks) {
                    short8 pa;
#pragma unroll
                    for (int half = 0; half < 2; ++half) {
                        f32x4 sv = st[2 * ks + half][qf];
#pragma unroll
                        for (int r = 0; r < 4; ++r) {
                            float p = __expf(sv[r] - mrun[qf]);
                            ls += p;
                            pa[half * 4 + r] = (short)f2bf(p);
                        }
                    }
                    pA[qf][ks] = pa;
                }
                ls += __shfl_xor(ls, 16);
                ls += __shfl_xor(ls, 32);
                lrun[qf] = lrun[qf] * alpha[qf] + ls;
            }
#pragma unroll
            for (int mf = 0; mf < 4; ++mf)
#pragma unroll
                for (int r = 0; r < 4; ++r) {
                    float aof = __shfl(alpha[mf], g * 4 + r);
#pragma unroll
                    for (int df = 0; df < 4; ++df)
                        o[mf][df][r] *= aof;
                }
#pragma unroll
            for (int ks = 0; ks < 2; ++ks) {
                short8 vB[4];
#pragma unroll
                for (int df = 0; df < 4; ++df)
                    vB[df] = *(short8*)&Vt[(df * 16 + c) * 72 + ks * 32 + g * 8];
#pragma unroll
                for (int mf = 0; mf < 4; ++mf)
#pragma unroll
                    for (int df = 0; df < 4; ++df)
                        o[mf][df] = __builtin_amdgcn_mfma_f32_16x16x32_bf16(pA[mf][ks], vB[df], o[mf][df], 0, 0, 0);
            }
        }
        __syncthreads();
    }
    const int bb = bh / H_, hh = bh % H_;
#pragma unroll
    for (int mf = 0; mf < 4; ++mf)
#pragma unroll
        for (int r = 0; r < 4; ++r) {
            float inv = 1.0f / __shfl(lrun[mf], g * 4 + r);
            int t = wid * 64 + mf * 16 + g * 4 + r;
#pragma unroll
            for (int df = 0; df < 4; ++df) {
                int d = df * 16 + c;
                ao[((size_t)(bb * T_ + t)) * C_ + hh * 64 + d] = f2bf(o[mf][df][r] * inv);
            }
        }
}

// ---------------- output projection: M=16384, N=384, K=384, + bias, fp32 out ----------------
__global__ __launch_bounds__(256, 2) void k_gemm_proj(const u16* __restrict__ ab, const u16* __restrict__ wp,
                                                      const float* __restrict__ bp, float* __restrict__ out) {
    __shared__ alignas(16) u16 lds[2][16384];
    const int tid = threadIdx.x, lane = tid & 63, wid = tid >> 6;
    const int wm = wid >> 1, wn = wid & 1, g = lane >> 4, c = lane & 15;
    const int n0 = blockIdx.x * 128, m0 = blockIdx.y * 128;
    const u16* Ag = ab + (size_t)m0 * 384;
    const u16* Bg = wp + (size_t)n0 * 384;
    f32x4 acc[4][4] = {};
    stage_tile(Ag, 384, &lds[0][0], wid, lane, 0);
    stage_tile(Bg, 384, &lds[0][8192], wid, lane, 0);
    GEMM_PIPE_LOOP(6)
#pragma unroll
    for (int mf = 0; mf < 4; ++mf)
#pragma unroll
        for (int nf = 0; nf < 4; ++nf)
#pragma unroll
            for (int r = 0; r < 4; ++r) {
                int m = m0 + wm * 64 + mf * 16 + g * 4 + r;
                int n = n0 + wn * 64 + nf * 16 + c;
                out[(size_t)m * C_ + n] = acc[mf][nf][r] + bp[n];
            }
}

// ---------------- host ----------------

extern "C" void kernel_launch(void* const* d_in, const int* in_sizes, int n_in,
                              void* d_out, int out_size, void* d_ws, size_t ws_size,
                              hipStream_t stream) {
    const float* x  = (const float*)d_in[0];
    const float* Wq = (const float*)d_in[1];
    const float* Wk = (const float*)d_in[2];
    const float* Wv = (const float*)d_in[3];
    const float* Wp = (const float*)d_in[4];
    const float* bp = (const float*)d_in[5];
    float* out = (float*)d_out;

    char* ws = (char*)d_ws;
    u16* xb   = (u16*)(ws);                    // 16384*384 bf16
    u16* wqkv = (u16*)(ws + 12582912);         // 1152*384
    u16* wpb  = (u16*)(ws + 13467648);         // 384*384
    u16* qb   = (u16*)(ws + 13762560);         // 64*6*256*64
    u16* kb   = (u16*)(ws + 26345472);
    u16* vb   = (u16*)(ws + 38928384);
    u16* ab   = (u16*)(ws + 51511296);         // 16384*384 bf16

    k_prep<<<3252, 256, 0, stream>>>(x, Wq, Wk, Wv, Wp, xb, wqkv, wpb);
    k_gemm_qkv<<<dim3(9, 128), 256, 0, stream>>>(xb, wqkv, qb, kb, vb);
    k_attn<<<384, 256, 0, stream>>>(qb, kb, vb, ab);
    k_gemm_proj<<<dim3(3, 128), 256, 0, stream>>>(ab, wpb, bp, out);
}